// Round 5
// baseline (428.262 us; speedup 1.0000x reference)
//
#include <hip/hip_runtime.h>
#include <stdint.h>

// Problem constants
constexpr int C      = 256;          // channels (in == out)
constexpr int H      = 28, W = 28;
constexpr int HW     = H * W;        // 784
constexpr int NB     = 64;           // batch
constexpr int WORDS  = 4;            // 256 / 64 bits
constexpr int CNT    = NB * HW;      // per-channel reduction count = 50176
constexpr int TOTAL  = NB * C * HW;  // 12,845,056
constexpr int COT    = 8;            // output-channel tile per block
constexpr int TW     = 30;           // padded tile width (28 + 2)
constexpr int TP     = TW * TW;      // 900 padded pixels

// ---------------------------------------------------------------------------
// Pack weight signs, TAP-MAJOR within each 8-channel group:
//   wb[((cg*9 + tap)*8 + co_l)*4 + wd],  cg = co/8, co_l = co%8
// plus P[co*9+tap] = popcount of the 256 weight sign bits for that tap
// (zero-padded-border correction).
// ---------------------------------------------------------------------------
__global__ void pack_w_kernel(const float* __restrict__ w, uint64_t* __restrict__ wb,
                              int* __restrict__ P) {
    int t = blockIdx.x * blockDim.x + threadIdx.x;  // co*9 + tap
    if (t >= C * 9) return;
    int tap = t % 9;
    int co  = t / 9;
    const float* base = w + (size_t)co * C * 9 + tap;
    uint64_t* dst = wb + (size_t)(((co >> 3) * 9 + tap) * 8 + (co & 7)) * WORDS;
    int ptot = 0;
#pragma unroll
    for (int wd = 0; wd < WORDS; ++wd) {
        uint64_t bits = 0;
        for (int j = 0; j < 64; ++j) {
            if (base[(size_t)(wd * 64 + j) * 9] < 0.f) bits |= (1ull << j);
        }
        dst[wd] = bits;
        ptot += __popcll(bits);
    }
    P[t] = ptot;
}

// ---------------------------------------------------------------------------
// Pack activation signs: x[n][c][h][w] -> xb[n][p][wd]  (p = h*W+w)
// (lanes cover consecutive p -> the (wd,j) loads are coalesced 256B/wave)
// ---------------------------------------------------------------------------
__global__ void pack_x_kernel(const float* __restrict__ x, uint64_t* __restrict__ xb) {
    int t = blockIdx.x * blockDim.x + threadIdx.x;  // n*HW + p
    if (t >= NB * HW) return;
    int n = t / HW, p = t % HW;
    const float* base = x + (size_t)n * C * HW + p;
    uint64_t* dst = xb + (size_t)t * WORDS;
#pragma unroll
    for (int wd = 0; wd < WORDS; ++wd) {
        uint64_t bits = 0;
#pragma unroll 8
        for (int j = 0; j < 64; ++j) {
            if (base[(size_t)(wd * 64 + j) * HW] < 0.f) bits |= (1ull << j);
        }
        dst[wd] = bits;
    }
}

// ---------------------------------------------------------------------------
// Fused BN(scale/shift) + binarize + pack (y1 stored as i16).
// sign(clip(z)) == sign(z), binarize(0)=+1, so only the sign of z matters.
// ---------------------------------------------------------------------------
__global__ void bn_signpack_kernel(const short* __restrict__ y,
                                   const float* __restrict__ scale,
                                   const float* __restrict__ shift,
                                   uint64_t* __restrict__ xb) {
    int t = blockIdx.x * blockDim.x + threadIdx.x;
    if (t >= NB * HW) return;
    int n = t / HW, p = t % HW;
    const short* base = y + (size_t)n * C * HW + p;
    uint64_t* dst = xb + (size_t)t * WORDS;
#pragma unroll
    for (int wd = 0; wd < WORDS; ++wd) {
        uint64_t bits = 0;
#pragma unroll 8
        for (int j = 0; j < 64; ++j) {
            int c = wd * 64 + j;
            float z = (float)base[(size_t)c * HW] * scale[c] + shift[c];
            if (z < 0.f) bits |= (1ull << j);
        }
        dst[wd] = bits;
    }
}

// ---------------------------------------------------------------------------
// Binary conv 3x3 pad=1, XNOR+popcount.
// TAP-OUTER K-loop (`#pragma unroll 1`): only one tap's weights (32 u64 =
// 64 VGPRs) are register-live at a time — blocks the LICM weight-hoist that
// caused R3's 256-VGPR spill.
// R4 post-mortem: EVERY index into acc/wr/qb must be compile-time constant,
// or LLVM demotes the whole array to scratch (R4: VGPR=84 + 38/80 MB of
// spill traffic, conv stuck at 129 us). Epilogue r-loop is therefore fully
// unrolled with an exec-mask guard for the tail rep.
// ---------------------------------------------------------------------------
template<bool HAS_RES, typename OUT_T>
__launch_bounds__(256, 3)   // VGPR cap 170: fits acc32+wr64+misc (~145), no spill
__global__ void bconv_kernel(const uint64_t* __restrict__ xb,
                             const uint64_t* __restrict__ wb,
                             const int* __restrict__ P,
                             const float* __restrict__ residual,
                             OUT_T* __restrict__ yout,
                             double* __restrict__ sum, double* __restrict__ sumsq) {
    __shared__ alignas(16) uint64_t xl[WORDS * TP];   // 28800 B, SoA
    __shared__ alignas(16) uint64_t wl[9 * COT * 4];  // 2304 B, tap-major
    __shared__ int Pl[COT * 9];
    __shared__ float red[64];

    const int n  = blockIdx.x;
    const int cg = blockIdx.y;   // channel group (8 channels)
    const int t  = threadIdx.x;

    // zero padded tile, then scatter interior (bit=0 encodes +1; border reads
    // as "all +1" and is corrected exactly via P)
    for (int i = t; i < WORDS * TP; i += 256) xl[i] = 0;
    __syncthreads();
    const uint64_t* xsrc = xb + (size_t)n * HW * WORDS;
    for (int i = t; i < HW * WORDS; i += 256) {
        int wd = i & 3, p = i >> 2;
        int q = (p / W) * TW + (p % W) + TW + 1;
        xl[wd * TP + q] = xsrc[i];
    }
    // 288 entries > 256 threads: MUST be strided (R2 bug)
    for (int i = t; i < 9 * COT * 4; i += 256) wl[i] = wb[(size_t)cg * (9 * COT * 4) + i];
    if (t < COT * 9) Pl[t] = P[cg * (COT * 9) + t];
    __syncthreads();

    // pixel assignment: p_r = t + 256*r; r=0..2 always valid, r=3 iff t<16
    int qb[4];
#pragma unroll
    for (int r = 0; r < 4; ++r) {
        int p = t + 256 * r;
        qb[r] = (p / W) * TW + (p % W);   // r=3 harmless if t>=16 (unused)
    }

    int acc[4][COT];
#pragma unroll
    for (int r = 0; r < 4; ++r)
#pragma unroll
        for (int co = 0; co < COT; ++co) acc[r][co] = 0;

#pragma unroll 1   // CRITICAL: keep taps a real loop — weight live-set stays 32 u64
    for (int tap = 0; tap < 9; ++tap) {
        const uint64_t* wt = &wl[tap * 32];
        uint64_t wr[32];
#pragma unroll
        for (int i = 0; i < 32; ++i) wr[i] = wt[i];   // 8x ds_read_b128, out of r-loop
        const int dq = (tap / 3) * TW + (tap % 3);

#pragma unroll
        for (int r = 0; r < 4; ++r) {
            if (r == 3 && t >= 16) continue;   // exec-mask, index stays constant
            const int q = qb[r] + dq;
            const uint64_t x0 = xl[q];
            const uint64_t x1 = xl[TP + q];
            const uint64_t x2 = xl[2 * TP + q];
            const uint64_t x3 = xl[3 * TP + q];
#pragma unroll
            for (int co = 0; co < COT; ++co) {
                acc[r][co] += __popcll(x0 ^ wr[co * 4 + 0]) + __popcll(x1 ^ wr[co * 4 + 1])
                            + __popcll(x2 ^ wr[co * 4 + 2]) + __popcll(x3 ^ wr[co * 4 + 3]);
            }
        }
    }

    // ---- epilogue: border correction, store, stats ----
    // FULLY UNROLLED r-loop: constant indices keep acc[] in registers (R4 bug)
    float sy[COT], sy2[COT];
#pragma unroll
    for (int co = 0; co < COT; ++co) { sy[co] = 0.f; sy2[co] = 0.f; }
    const size_t obase_n = ((size_t)n * C + (size_t)cg * COT) * HW;

#pragma unroll
    for (int r = 0; r < 4; ++r) {
        if (r == 3 && t >= 16) continue;   // exec-mask guard, not dynamic index
        const int p = t + 256 * r;
        const int oh = p / W, ow = p - oh * W;
        int basev = 9 * 256;
        if (oh == 0 || oh == H - 1 || ow == 0 || ow == W - 1) {
#pragma unroll
            for (int kh = 0; kh < 3; ++kh)
#pragma unroll
                for (int kw = 0; kw < 3; ++kw) {
                    const int ih = oh + kh - 1, iw = ow + kw - 1;
                    if ((unsigned)ih >= (unsigned)H || (unsigned)iw >= (unsigned)W) {
                        basev -= 256;
#pragma unroll
                        for (int co = 0; co < COT; ++co)
                            acc[r][co] -= Pl[co * 9 + kh * 3 + kw];
                    }
                }
        }
#pragma unroll
        for (int co = 0; co < COT; ++co) {
            float y = (float)(basev - 2 * acc[r][co]);
            const size_t oidx = obase_n + (size_t)co * HW + p;
            if (HAS_RES) y += residual[oidx];
            yout[oidx] = (OUT_T)y;
            sy[co] += y;
            sy2[co] += y * y;
        }
    }

    // block reduction of 8 channel sums + 8 sumsq
    const int lane = t & 63, wave = t >> 6;
#pragma unroll
    for (int k = 0; k < 16; ++k) {
        float s = (k < 8) ? sy[k] : sy2[k - 8];
#pragma unroll
        for (int off = 32; off; off >>= 1) s += __shfl_down(s, off);
        if (lane == 0) red[wave * 16 + k] = s;
    }
    __syncthreads();
    if (t < 16) {
        double tot = (double)red[t] + (double)red[16 + t]
                   + (double)red[32 + t] + (double)red[48 + t];
        if (t < 8) atomicAdd(&sum[cg * COT + t], tot);
        else       atomicAdd(&sumsq[cg * COT + t - 8], tot);
    }
}

// ---------------------------------------------------------------------------
// BN stats -> per-channel scale/shift (fp64 internally)
// ---------------------------------------------------------------------------
__global__ void finalize_kernel(const double* __restrict__ sum,
                                const double* __restrict__ sumsq,
                                const float* __restrict__ gamma,
                                const float* __restrict__ beta,
                                float* __restrict__ scale,
                                float* __restrict__ shift) {
    int c = threadIdx.x;  // 256 threads
    double mean = sum[c] / (double)CNT;
    double var  = sumsq[c] / (double)CNT - mean * mean;
    double inv  = 1.0 / sqrt(var + 1e-5);
    float sc = (float)inv * gamma[c];
    scale[c] = sc;
    shift[c] = beta[c] - (float)(mean * inv) * gamma[c];
}

// ---------------------------------------------------------------------------
// Final: out = clip(z*scale[c] + shift[c], -1, 1), float4 vectorized
// (HW = 784 = 4*196, so a float4 never crosses a channel boundary)
// ---------------------------------------------------------------------------
__global__ void bn_clip_kernel(const float4* __restrict__ z,
                               const float* __restrict__ scale,
                               const float* __restrict__ shift,
                               float4* __restrict__ out, int total4) {
    for (int i = blockIdx.x * blockDim.x + threadIdx.x; i < total4;
         i += gridDim.x * blockDim.x) {
        int c = (i / (HW / 4)) & (C - 1);
        float s = scale[c], b = shift[c];
        float4 v = z[i];
        v.x = fminf(1.f, fmaxf(-1.f, v.x * s + b));
        v.y = fminf(1.f, fmaxf(-1.f, v.y * s + b));
        v.z = fminf(1.f, fmaxf(-1.f, v.z * s + b));
        v.w = fminf(1.f, fmaxf(-1.f, v.w * s + b));
        out[i] = v;
    }
}

// ---------------------------------------------------------------------------
extern "C" void kernel_launch(void* const* d_in, const int* in_sizes, int n_in,
                              void* d_out, int out_size, void* d_ws, size_t ws_size,
                              hipStream_t stream) {
    const float* x  = (const float*)d_in[0];
    const float* w1 = (const float*)d_in[1];
    const float* w2 = (const float*)d_in[2];
    const float* g1 = (const float*)d_in[3];
    const float* b1 = (const float*)d_in[4];
    const float* g2 = (const float*)d_in[5];
    const float* b2 = (const float*)d_in[6];
    float* out = (float*)d_out;

    char* ws = (char*)d_ws;
    size_t off = 0;
    float* z2 = (float*)(ws + off);          off += (size_t)TOTAL * 4;            // 51.4 MB
    uint64_t* xb1 = (uint64_t*)(ws + off);   off += (size_t)NB * HW * WORDS * 8;  // 1.6 MB
    uint64_t* xb2 = (uint64_t*)(ws + off);   off += (size_t)NB * HW * WORDS * 8;
    uint64_t* wb1 = (uint64_t*)(ws + off);   off += (size_t)C * 9 * WORDS * 8;    // 73 KB
    uint64_t* wb2 = (uint64_t*)(ws + off);   off += (size_t)C * 9 * WORDS * 8;
    int* P1 = (int*)(ws + off);              off += (size_t)C * 9 * 4;
    int* P2 = (int*)(ws + off);              off += (size_t)C * 9 * 4;
    double* stats = (double*)(ws + off);     off += 4 * 256 * 8;
    double* sum1 = stats, *sumsq1 = stats + 256, *sum2 = stats + 512, *sumsq2 = stats + 768;
    float* coefs = (float*)(ws + off);       off += 4 * 256 * 4;
    float* scale1 = coefs, *shift1 = coefs + 256, *scale2 = coefs + 512, *shift2 = coefs + 768;

    // y1 (i16) lives in d_out as scratch; fully rewritten by bn_clip at the end
    short* y1 = (short*)d_out;

    // zero the fp64 stat accumulators (ws is re-poisoned before every launch)
    hipMemsetAsync(stats, 0, 4 * 256 * 8, stream);

    // pack weights + input signs
    pack_w_kernel<<<(C * 9 + 255) / 256, 256, 0, stream>>>(w1, wb1, P1);
    pack_w_kernel<<<(C * 9 + 255) / 256, 256, 0, stream>>>(w2, wb2, P2);
    pack_x_kernel<<<(NB * HW + 255) / 256, 256, 0, stream>>>(x, xb1);

    dim3 cgrid(NB, C / COT);
    // conv1: y1 (i16) -> d_out scratch, fused BN1 stats
    bconv_kernel<false, short><<<cgrid, 256, 0, stream>>>(xb1, wb1, P1, nullptr, y1, sum1, sumsq1);
    finalize_kernel<<<1, 256, 0, stream>>>(sum1, sumsq1, g1, b1, scale1, shift1);
    // BN1 + hardtanh + binarize collapse to sign(BN1) -> bit-pack
    bn_signpack_kernel<<<(NB * HW + 255) / 256, 256, 0, stream>>>(y1, scale1, shift1, xb2);
    // conv2 + residual, fused BN2 stats, z2 -> ws
    bconv_kernel<true, float><<<cgrid, 256, 0, stream>>>(xb2, wb2, P2, x, z2, sum2, sumsq2);
    finalize_kernel<<<1, 256, 0, stream>>>(sum2, sumsq2, g2, b2, scale2, shift2);
    // BN2 + hardtanh -> out
    bn_clip_kernel<<<4096, 256, 0, stream>>>((const float4*)z2, scale2, shift2,
                                             (float4*)out, TOTAL / 4);
}

// Round 6
// 391.518 us; speedup vs baseline: 1.0939x; 1.0939x over previous
//
#include <hip/hip_runtime.h>
#include <stdint.h>

typedef unsigned long long u64;

// Problem constants
constexpr int C      = 256;          // channels (in == out)
constexpr int H      = 28, W = 28;
constexpr int HW     = H * W;        // 784
constexpr int NB     = 64;           // batch
constexpr int WORDS  = 4;            // 256 / 64 bits
constexpr int CNT    = NB * HW;      // per-channel reduction count = 50176
constexpr int TOTAL  = NB * C * HW;  // 12,845,056
constexpr int COT    = 8;            // output-channel tile per block
constexpr int TW     = 30;           // padded tile width (28 + 2)
constexpr int TP     = TW * TW;      // 900 padded pixels

// ---------------------------------------------------------------------------
// Pack weight signs, TAP-MAJOR within each 8-channel group:
//   wb[((cg*9 + tap)*8 + co_l)*4 + wd],  cg = co/8, co_l = co%8
// plus P[co*9+tap] = popcount of the 256 weight sign bits for that tap
// (zero-padded-border correction).
// ---------------------------------------------------------------------------
__global__ void pack_w_kernel(const float* __restrict__ w, uint64_t* __restrict__ wb,
                              int* __restrict__ P) {
    int t = blockIdx.x * blockDim.x + threadIdx.x;  // co*9 + tap
    if (t >= C * 9) return;
    int tap = t % 9;
    int co  = t / 9;
    const float* base = w + (size_t)co * C * 9 + tap;
    uint64_t* dst = wb + (size_t)(((co >> 3) * 9 + tap) * 8 + (co & 7)) * WORDS;
    int ptot = 0;
#pragma unroll
    for (int wd = 0; wd < WORDS; ++wd) {
        uint64_t bits = 0;
        for (int j = 0; j < 64; ++j) {
            if (base[(size_t)(wd * 64 + j) * 9] < 0.f) bits |= (1ull << j);
        }
        dst[wd] = bits;
        ptot += __popcll(bits);
    }
    P[t] = ptot;
}

// ---------------------------------------------------------------------------
// Pack activation signs: x[n][c][h][w] -> xb[n][p][wd]  (p = h*W+w)
// ---------------------------------------------------------------------------
__global__ void pack_x_kernel(const float* __restrict__ x, uint64_t* __restrict__ xb) {
    int t = blockIdx.x * blockDim.x + threadIdx.x;  // n*HW + p
    if (t >= NB * HW) return;
    int n = t / HW, p = t % HW;
    const float* base = x + (size_t)n * C * HW + p;
    uint64_t* dst = xb + (size_t)t * WORDS;
#pragma unroll
    for (int wd = 0; wd < WORDS; ++wd) {
        uint64_t bits = 0;
#pragma unroll 8
        for (int j = 0; j < 64; ++j) {
            if (base[(size_t)(wd * 64 + j) * HW] < 0.f) bits |= (1ull << j);
        }
        dst[wd] = bits;
    }
}

// ---------------------------------------------------------------------------
// Fused BN(scale/shift) + binarize + pack (y1 stored as i16).
// sign(clip(z)) == sign(z), binarize(0)=+1, so only the sign of z matters.
// ---------------------------------------------------------------------------
__global__ void bn_signpack_kernel(const short* __restrict__ y,
                                   const float* __restrict__ scale,
                                   const float* __restrict__ shift,
                                   uint64_t* __restrict__ xb) {
    int t = blockIdx.x * blockDim.x + threadIdx.x;
    if (t >= NB * HW) return;
    int n = t / HW, p = t % HW;
    const short* base = y + (size_t)n * C * HW + p;
    uint64_t* dst = xb + (size_t)t * WORDS;
#pragma unroll
    for (int wd = 0; wd < WORDS; ++wd) {
        uint64_t bits = 0;
#pragma unroll 8
        for (int j = 0; j < 64; ++j) {
            int c = wd * 64 + j;
            float z = (float)base[(size_t)c * HW] * scale[c] + shift[c];
            if (z < 0.f) bits |= (1ull << j);
        }
        dst[wd] = bits;
    }
}

// ---------------------------------------------------------------------------
// Binary conv 3x3 pad=1, XNOR+popcount.
// R5 post-mortem: private ARRAYS (wr[32], acc[4][8]) are never promoted by
// SROA (it runs before late unrolling) -> scratch traffic, VGPR stuck at 84,
// 124 us. Fix: NO private arrays at all — named scalars via token-pasting
// macros. Border fixup moved to a precomputed LDS table Tl[mask][co]
// (dynamic LDS indexing is fine; private-array indexing is not).
// Tap-outer `#pragma unroll 1` keeps weight live-set at 32 u64 (R3 lesson).
// ---------------------------------------------------------------------------

// weights: w{co}{wd}, accumulators: a{r}{co}, stats: sy{co}, sq{co}
#define W_DECL(co) u64 w##co##0, w##co##1, w##co##2, w##co##3;
#define W_LOAD(co) w##co##0 = wt[(co)*4+0]; w##co##1 = wt[(co)*4+1]; \
                   w##co##2 = wt[(co)*4+2]; w##co##3 = wt[(co)*4+3];
#define A_DECL(r) int a##r##0=0, a##r##1=0, a##r##2=0, a##r##3=0, \
                      a##r##4=0, a##r##5=0, a##r##6=0, a##r##7=0;
#define ACC1(r, co) a##r##co += __popcll(x0 ^ w##co##0) + __popcll(x1 ^ w##co##1) \
                              + __popcll(x2 ^ w##co##2) + __popcll(x3 ^ w##co##3);
#define ACC_ALL(r) ACC1(r,0) ACC1(r,1) ACC1(r,2) ACC1(r,3) \
                   ACC1(r,4) ACC1(r,5) ACC1(r,6) ACC1(r,7)
#define DO_R(r) { const int q = qb##r + dq; \
    const u64 x0 = xl[q], x1 = xl[TP+q], x2 = xl[2*TP+q], x3 = xl[3*TP+q]; \
    ACC_ALL(r) }
#define EPI1(r, co) { \
    float y = (float)(Tl[mk + co] - 2 * a##r##co); \
    const size_t oidx = obase_n + (size_t)(co) * HW + pp; \
    if (HAS_RES) y += residual[oidx]; \
    yout[oidx] = (OUT_T)y; \
    sy##co += y; sq##co += y * y; }
#define EPI_R(r) { const int pp = t + 256 * (r); \
    const int oh = pp / W, ow = pp - oh * W; \
    const int mk = (((oh==0)?0:((oh==H-1)?2:1))*3 + ((ow==0)?0:((ow==W-1)?2:1))) * COT; \
    EPI1(r,0) EPI1(r,1) EPI1(r,2) EPI1(r,3) EPI1(r,4) EPI1(r,5) EPI1(r,6) EPI1(r,7) }
#define RED(co) { float s1 = sy##co, s2 = sq##co; \
    _Pragma("unroll") \
    for (int off = 32; off; off >>= 1) { s1 += __shfl_down(s1, off); s2 += __shfl_down(s2, off); } \
    if (lane == 0) { red[wave*16 + co] = s1; red[wave*16 + 8 + co] = s2; } }

template<bool HAS_RES, typename OUT_T>
__launch_bounds__(256, 3)   // VGPR cap ~170; est. live set ~135
__global__ void bconv_kernel(const uint64_t* __restrict__ xb,
                             const uint64_t* __restrict__ wb,
                             const int* __restrict__ P,
                             const float* __restrict__ residual,
                             OUT_T* __restrict__ yout,
                             double* __restrict__ sum, double* __restrict__ sumsq) {
    __shared__ alignas(16) uint64_t xl[WORDS * TP];   // 28800 B, SoA
    __shared__ alignas(16) uint64_t wl[9 * COT * 4];  // 2304 B, tap-major
    __shared__ int Tl[9 * COT];                       // border-corrected base per (mask,co)
    __shared__ float red[64];

    const int n  = blockIdx.x;
    const int cg = blockIdx.y;   // channel group (8 channels)
    const int t  = threadIdx.x;

    // zero padded tile, then scatter interior (bit=0 encodes +1; border reads
    // as "all +1" and is corrected exactly via Tl)
    for (int i = t; i < WORDS * TP; i += 256) xl[i] = 0;
    __syncthreads();
    const uint64_t* xsrc = xb + (size_t)n * HW * WORDS;
    for (int i = t; i < HW * WORDS; i += 256) {
        int wd = i & 3, p = i >> 2;
        int q = (p / W) * TW + (p % W) + TW + 1;
        xl[wd * TP + q] = xsrc[i];
    }
    // 288 entries > 256 threads: strided (R2 bug)
    for (int i = t; i < 9 * COT * 4; i += 256) wl[i] = wb[(size_t)cg * (9 * COT * 4) + i];
    // Tl[mask*8+co] = 9*256 - sum over taps invalid for this border-mask of
    // (256 - 2*P[co][tap]); mask = mrow*3+mcol, mrow/mcol in {0:first,1:mid,2:last}
    if (t < 9 * COT) {
        const int co = t / 9, mask = t % 9;
        const int mr = mask / 3, mc = mask % 3;
        const int* Pg = P + cg * (COT * 9) + co * 9;
        int val = 9 * 256;
        for (int kh = 0; kh < 3; ++kh)
            for (int kw = 0; kw < 3; ++kw) {
                bool inv = (mr == 0 && kh == 0) || (mr == 2 && kh == 2) ||
                           (mc == 0 && kw == 0) || (mc == 2 && kw == 2);
                if (inv) val -= (256 - 2 * Pg[kh * 3 + kw]);
            }
        Tl[mask * COT + co] = val;
    }
    __syncthreads();

    // pixel assignment: p_r = t + 256*r; r=0..2 always valid, r=3 iff t<16
    const int p0 = t, p1 = t + 256, p2 = t + 512, p3 = t + 768;
    const int qb0 = (p0 / W) * TW + (p0 % W);
    const int qb1 = (p1 / W) * TW + (p1 % W);
    const int qb2 = (p2 / W) * TW + (p2 % W);
    const int qb3 = (p3 / W) * TW + (p3 % W);   // unused lanes t>=16: harmless

    A_DECL(0) A_DECL(1) A_DECL(2) A_DECL(3)

#pragma unroll 1   // keep taps a real loop — weight live-set stays 32 u64
    for (int tap = 0; tap < 9; ++tap) {
        const uint64_t* wt = &wl[tap * 32];
        W_DECL(0) W_DECL(1) W_DECL(2) W_DECL(3)
        W_DECL(4) W_DECL(5) W_DECL(6) W_DECL(7)
        W_LOAD(0) W_LOAD(1) W_LOAD(2) W_LOAD(3)
        W_LOAD(4) W_LOAD(5) W_LOAD(6) W_LOAD(7)
        const int dq = (tap / 3) * TW + (tap % 3);
        DO_R(0) DO_R(1) DO_R(2)
        if (t < 16) { DO_R(3) }
    }

    // ---- epilogue: table-corrected store + stats, all named scalars ----
    float sy0=0,sy1=0,sy2=0,sy3=0,sy4=0,sy5=0,sy6=0,sy7=0;
    float sq0=0,sq1=0,sq2=0,sq3=0,sq4=0,sq5=0,sq6=0,sq7=0;
    const size_t obase_n = ((size_t)n * C + (size_t)cg * COT) * HW;

    EPI_R(0) EPI_R(1) EPI_R(2)
    if (t < 16) { EPI_R(3) }

    // block reduction of 8 channel sums + 8 sumsq
    const int lane = t & 63, wave = t >> 6;
    RED(0) RED(1) RED(2) RED(3) RED(4) RED(5) RED(6) RED(7)
    __syncthreads();
    if (t < 16) {
        double tot = (double)red[t] + (double)red[16 + t]
                   + (double)red[32 + t] + (double)red[48 + t];
        if (t < 8) atomicAdd(&sum[cg * COT + t], tot);
        else       atomicAdd(&sumsq[cg * COT + t - 8], tot);
    }
}

// ---------------------------------------------------------------------------
// BN stats -> per-channel scale/shift (fp64 internally)
// ---------------------------------------------------------------------------
__global__ void finalize_kernel(const double* __restrict__ sum,
                                const double* __restrict__ sumsq,
                                const float* __restrict__ gamma,
                                const float* __restrict__ beta,
                                float* __restrict__ scale,
                                float* __restrict__ shift) {
    int c = threadIdx.x;  // 256 threads
    double mean = sum[c] / (double)CNT;
    double var  = sumsq[c] / (double)CNT - mean * mean;
    double inv  = 1.0 / sqrt(var + 1e-5);
    float sc = (float)inv * gamma[c];
    scale[c] = sc;
    shift[c] = beta[c] - (float)(mean * inv) * gamma[c];
}

// ---------------------------------------------------------------------------
// Final: out = clip(z*scale[c] + shift[c], -1, 1), float4 vectorized
// ---------------------------------------------------------------------------
__global__ void bn_clip_kernel(const float4* __restrict__ z,
                               const float* __restrict__ scale,
                               const float* __restrict__ shift,
                               float4* __restrict__ out, int total4) {
    for (int i = blockIdx.x * blockDim.x + threadIdx.x; i < total4;
         i += gridDim.x * blockDim.x) {
        int c = (i / (HW / 4)) & (C - 1);
        float s = scale[c], b = shift[c];
        float4 v = z[i];
        v.x = fminf(1.f, fmaxf(-1.f, v.x * s + b));
        v.y = fminf(1.f, fmaxf(-1.f, v.y * s + b));
        v.z = fminf(1.f, fmaxf(-1.f, v.z * s + b));
        v.w = fminf(1.f, fmaxf(-1.f, v.w * s + b));
        out[i] = v;
    }
}

// ---------------------------------------------------------------------------
extern "C" void kernel_launch(void* const* d_in, const int* in_sizes, int n_in,
                              void* d_out, int out_size, void* d_ws, size_t ws_size,
                              hipStream_t stream) {
    const float* x  = (const float*)d_in[0];
    const float* w1 = (const float*)d_in[1];
    const float* w2 = (const float*)d_in[2];
    const float* g1 = (const float*)d_in[3];
    const float* b1 = (const float*)d_in[4];
    const float* g2 = (const float*)d_in[5];
    const float* b2 = (const float*)d_in[6];
    float* out = (float*)d_out;

    char* ws = (char*)d_ws;
    size_t off = 0;
    float* z2 = (float*)(ws + off);          off += (size_t)TOTAL * 4;            // 51.4 MB
    uint64_t* xb1 = (uint64_t*)(ws + off);   off += (size_t)NB * HW * WORDS * 8;  // 1.6 MB
    uint64_t* xb2 = (uint64_t*)(ws + off);   off += (size_t)NB * HW * WORDS * 8;
    uint64_t* wb1 = (uint64_t*)(ws + off);   off += (size_t)C * 9 * WORDS * 8;    // 73 KB
    uint64_t* wb2 = (uint64_t*)(ws + off);   off += (size_t)C * 9 * WORDS * 8;
    int* P1 = (int*)(ws + off);              off += (size_t)C * 9 * 4;
    int* P2 = (int*)(ws + off);              off += (size_t)C * 9 * 4;
    double* stats = (double*)(ws + off);     off += 4 * 256 * 8;
    double* sum1 = stats, *sumsq1 = stats + 256, *sum2 = stats + 512, *sumsq2 = stats + 768;
    float* coefs = (float*)(ws + off);       off += 4 * 256 * 4;
    float* scale1 = coefs, *shift1 = coefs + 256, *scale2 = coefs + 512, *shift2 = coefs + 768;

    // y1 (i16) lives in d_out as scratch; fully rewritten by bn_clip at the end
    short* y1 = (short*)d_out;

    // zero the fp64 stat accumulators (ws is re-poisoned before every launch)
    hipMemsetAsync(stats, 0, 4 * 256 * 8, stream);

    // pack weights + input signs
    pack_w_kernel<<<(C * 9 + 255) / 256, 256, 0, stream>>>(w1, wb1, P1);
    pack_w_kernel<<<(C * 9 + 255) / 256, 256, 0, stream>>>(w2, wb2, P2);
    pack_x_kernel<<<(NB * HW + 255) / 256, 256, 0, stream>>>(x, xb1);

    dim3 cgrid(NB, C / COT);
    // conv1: y1 (i16) -> d_out scratch, fused BN1 stats
    bconv_kernel<false, short><<<cgrid, 256, 0, stream>>>(xb1, wb1, P1, nullptr, y1, sum1, sumsq1);
    finalize_kernel<<<1, 256, 0, stream>>>(sum1, sumsq1, g1, b1, scale1, shift1);
    // BN1 + hardtanh + binarize collapse to sign(BN1) -> bit-pack
    bn_signpack_kernel<<<(NB * HW + 255) / 256, 256, 0, stream>>>(y1, scale1, shift1, xb2);
    // conv2 + residual, fused BN2 stats, z2 -> ws
    bconv_kernel<true, float><<<cgrid, 256, 0, stream>>>(xb2, wb2, P2, x, z2, sum2, sumsq2);
    finalize_kernel<<<1, 256, 0, stream>>>(sum2, sumsq2, g2, b2, scale2, shift2);
    // BN2 + hardtanh -> out
    bn_clip_kernel<<<4096, 256, 0, stream>>>((const float4*)z2, scale2, shift2,
                                             (float4*)out, TOTAL / 4);
}